// Round 14
// baseline (190.633 us; speedup 1.0000x reference)
//
#include <hip/hip_runtime.h>

#define N_NODES 100000
#define D 64
#define N_EDGES 1200000
#define NCB 391              // coarse buckets of 256 dst nodes
#define NBLK 256             // partition blocks
#define CHUNK ((N_EDGES + NBLK - 1) / NBLK)   // 4688 edges per block

typedef __attribute__((ext_vector_type(8))) short short8v;           // 8 bf16 (MFMA frag)
typedef __attribute__((ext_vector_type(8))) unsigned short ushort8v; // 8 bf16 raw
typedef __attribute__((ext_vector_type(4))) float f32x4;

__device__ __forceinline__ unsigned short f2bf(float x) {
    unsigned int b = __float_as_uint(x);
    b += 0x7FFFu + ((b >> 16) & 1u);          // round-to-nearest-even
    return (unsigned short)(b >> 16);
}
__device__ __forceinline__ float bf2f(unsigned short u) {
    return __uint_as_float((unsigned int)u << 16);
}

// ---------- pass 1: per-block coarse histogram + fb + wb ----------
__global__ __launch_bounds__(256) void bin_hist(
    const int* __restrict__ eidx, int* __restrict__ hist,
    const float* __restrict__ feat, ushort* __restrict__ fb,
    const float* __restrict__ W, ushort* __restrict__ wb)
{
    __shared__ int h[NCB];
    for (int i = threadIdx.x; i < NCB; i += 256) h[i] = 0;
    __syncthreads();
    const int blk = blockIdx.x;

    // W fragment table: wb[t][c4][lane][j] = bf16(W[32t+(lane>>4)*8+j][16c4+(lane&15)])
    if (blk < 32) {
        int g  = blk * 256 + threadIdx.x;     // 0..8191
        int j  = g & 7;
        int l  = (g >> 3) & 63;
        int c4 = (g >> 9) & 3;
        int tt = g >> 11;
        int k   = 32 * tt + ((l >> 4) << 3) + j;
        int col = 16 * c4 + (l & 15);
        wb[g] = f2bf(W[k * 64 + col]);
    }

    const int beg = blk * CHUNK;
    const int end = min(beg + CHUNK, N_EDGES);
    for (int e = beg + threadIdx.x; e < end; e += 256)
        atomicAdd(&h[eidx[N_EDGES + e] >> 8], 1);

    // folded bf16 conversion of the feature table
    const int total4 = N_NODES * D / 4;
    for (int i = blk * 256 + threadIdx.x; i < total4; i += NBLK * 256) {
        float4 v = ((const float4*)feat)[i];
        ushort4 o;
        o.x = f2bf(v.x); o.y = f2bf(v.y); o.z = f2bf(v.z); o.w = f2bf(v.w);
        ((ushort4*)fb)[i] = o;
    }

    __syncthreads();
    for (int i = threadIdx.x; i < NCB; i += 256)
        hist[blk * NCB + i] = h[i];
}

// ---------- pass 2: bucket bases + per-(block,bucket) run starts (parallel) ----------
// block i: bo_i = sum over all (blk, j<i) of hist[blk][j]  (hist is L2-hot);
// then column scan of hist[.][i] over the 256 partition blocks.
__global__ __launch_bounds__(256) void rstart(
    const int* __restrict__ hist,
    int* __restrict__ boff, int* __restrict__ runstart, int* __restrict__ offs)
{
    __shared__ int red[256];
    __shared__ int pfx[256];
    __shared__ int bo_s;

    const int tid = threadIdx.x;
    const int i   = blockIdx.x;

    int p = 0;
    for (int blk = 0; blk < NBLK; ++blk)
        for (int j = tid; j < i; j += 256)
            p += hist[blk * NCB + j];
    red[tid] = p;
    __syncthreads();
    for (int off = 128; off > 0; off >>= 1) {
        if (tid < off) red[tid] += red[tid + off];
        __syncthreads();
    }
    if (tid == 0) {
        bo_s = red[0];
        boff[i] = red[0];
        if (i == 0) { boff[NCB] = N_EDGES; offs[N_NODES] = N_EDGES; }
    }
    __syncthreads();

    int v = hist[tid * NCB + i];
    pfx[tid] = v;
    __syncthreads();
    for (int off = 1; off < 256; off <<= 1) {
        int x = (tid >= off) ? pfx[tid - off] : 0;
        __syncthreads();
        pfx[tid] += x;
        __syncthreads();
    }
    runstart[tid * NCB + i] = bo_s + pfx[tid] - v;
}

// ---------- pass 3: deterministic scatter into per-block sub-ranges ----------
__global__ __launch_bounds__(256) void bin_fill(
    const int* __restrict__ eidx, const int* __restrict__ runstart,
    unsigned int* __restrict__ pairs)
{
    __shared__ int lcur[NCB];
    const int blk = blockIdx.x;
    for (int i = threadIdx.x; i < NCB; i += 256) lcur[i] = runstart[blk * NCB + i];
    __syncthreads();
    const int beg = blk * CHUNK;
    const int end = min(beg + CHUNK, N_EDGES);
    for (int e = beg + threadIdx.x; e < end; e += 256) {
        int src = eidx[e];
        int dst = eidx[N_EDGES + e];
        int pos = atomicAdd(&lcur[dst >> 8], 1);
        pairs[pos] = ((unsigned int)src << 8) | (unsigned int)(dst & 255);
    }
}

// ---------- pass 4: fine sort within bucket -> offs[] + csr[] ----------
__global__ __launch_bounds__(256) void fine_sort(
    const unsigned int* __restrict__ pairs,
    const int* __restrict__ boff,
    int* __restrict__ offs,
    int* __restrict__ csr)
{
    __shared__ int cnt[256];
    __shared__ int pfx[256];
    __shared__ int lcur[256];

    const int tid = threadIdx.x;
    const int b   = blockIdx.x;
    const int beg = boff[b];
    const int end = boff[b + 1];

    cnt[tid] = 0;
    __syncthreads();
    for (int j = beg + tid; j < end; j += 256)
        atomicAdd(&cnt[pairs[j] & 255], 1);
    __syncthreads();

    int v = cnt[tid];
    pfx[tid] = v;
    __syncthreads();
    for (int off = 1; off < 256; off <<= 1) {
        int x = (tid >= off) ? pfx[tid - off] : 0;
        __syncthreads();
        pfx[tid] += x;
        __syncthreads();
    }
    int ex = pfx[tid] - v;
    lcur[tid] = ex;
    int gn = b * 256 + tid;
    if (gn < N_NODES) offs[gn] = beg + ex;
    __syncthreads();

    for (int j = beg + tid; j < end; j += 256) {
        unsigned int p = pairs[j];
        int pos = beg + atomicAdd(&lcur[p & 255], 1);
        csr[pos] = (int)(p >> 8);
    }
}

// ---------- fused aggregate + MFMA linear: block = 32 nodes ----------
// Phase A: octet (8 lanes) per node, ushort8 (16B) gathers -> 64 rows in
// flight per wave; mean (bf16) -> LDS (4.6KB only -> high occupancy).
// Phase B: 4 waves x 2 MFMA tiles; B-frags straight from global wb (L2-hot).
#define MROW 72   // means row stride in ushorts (144B, 16B-aligned)
#define S8(j) (((bf2f(v0[j])+bf2f(v1[j]))+(bf2f(v2[j])+bf2f(v3[j]))) \
             + ((bf2f(v4[j])+bf2f(v5[j]))+(bf2f(v6[j])+bf2f(v7[j]))))
#define S4(j) ((bf2f(v0[j])+bf2f(v1[j]))+(bf2f(v2[j])+bf2f(v3[j])))
__global__ __launch_bounds__(256) void agg_gemm(
    const ushort* __restrict__ fb,
    const int* __restrict__ offs,
    const int* __restrict__ csr,
    const ushort* __restrict__ wb,
    const float* __restrict__ bias,
    float* __restrict__ out)
{
    __shared__ __attribute__((aligned(16))) ushort means[32 * MROW];

    const int tid = threadIdx.x;
    const int n0  = blockIdx.x * 32;

    // ----- Phase A: gather -----
    const int l    = tid & 7;                 // lane within octet (dims 8l..8l+7)
    const int node = tid >> 3;                // 0..31
    const int n    = n0 + node;

    const int beg = offs[n];
    const int end = offs[n + 1];
    const ushort8v* f8 = (const ushort8v*)fb;   // row stride = 8 ushort8v

    float s0=0.f,s1=0.f,s2=0.f,s3=0.f,s4=0.f,s5=0.f,s6=0.f,s7=0.f;
    int e = beg;
    for (; e + 8 <= end; e += 8) {
        int i0=csr[e+0], i1=csr[e+1], i2=csr[e+2], i3=csr[e+3];
        int i4=csr[e+4], i5=csr[e+5], i6=csr[e+6], i7=csr[e+7];
        ushort8v v0 = f8[(size_t)i0 * 8 + l];
        ushort8v v1 = f8[(size_t)i1 * 8 + l];
        ushort8v v2 = f8[(size_t)i2 * 8 + l];
        ushort8v v3 = f8[(size_t)i3 * 8 + l];
        ushort8v v4 = f8[(size_t)i4 * 8 + l];
        ushort8v v5 = f8[(size_t)i5 * 8 + l];
        ushort8v v6 = f8[(size_t)i6 * 8 + l];
        ushort8v v7 = f8[(size_t)i7 * 8 + l];
        s0 += S8(0); s1 += S8(1); s2 += S8(2); s3 += S8(3);
        s4 += S8(4); s5 += S8(5); s6 += S8(6); s7 += S8(7);
    }
    for (; e + 4 <= end; e += 4) {
        int i0=csr[e+0], i1=csr[e+1], i2=csr[e+2], i3=csr[e+3];
        ushort8v v0 = f8[(size_t)i0 * 8 + l];
        ushort8v v1 = f8[(size_t)i1 * 8 + l];
        ushort8v v2 = f8[(size_t)i2 * 8 + l];
        ushort8v v3 = f8[(size_t)i3 * 8 + l];
        s0 += S4(0); s1 += S4(1); s2 += S4(2); s3 += S4(3);
        s4 += S4(4); s5 += S4(5); s6 += S4(6); s7 += S4(7);
    }
    for (; e < end; ++e) {
        ushort8v v0 = f8[(size_t)csr[e] * 8 + l];
        s0 += bf2f(v0[0]); s1 += bf2f(v0[1]); s2 += bf2f(v0[2]); s3 += bf2f(v0[3]);
        s4 += bf2f(v0[4]); s5 += bf2f(v0[5]); s6 += bf2f(v0[6]); s7 += bf2f(v0[7]);
    }

    float dg = (float)(end - beg);
    dg = dg > 1.0f ? dg : 1.0f;
    float inv = 1.0f / dg;
    {
        ushort8v m;
        m[0]=f2bf(s0*inv); m[1]=f2bf(s1*inv); m[2]=f2bf(s2*inv); m[3]=f2bf(s3*inv);
        m[4]=f2bf(s4*inv); m[5]=f2bf(s5*inv); m[6]=f2bf(s6*inv); m[7]=f2bf(s7*inv);
        *(ushort8v*)(means + node * MROW + l * 8) = m;
    }
    __syncthreads();

    // ----- Phase B: MFMA. wave wv: row-tile rt = wv>>1 (16 nodes), col pair wv&1 -----
    const int lane = tid & 63;
    const int wv   = tid >> 6;
    const int rt   = wv >> 1;
    const int cp   = wv & 1;
    const int kg   = lane >> 4;
    const int cl   = lane & 15;

    const ushort* frow = fb + (size_t)(n0 + rt * 16 + cl) * 64;
    const ushort* mrow = means + (rt * 16 + cl) * MROW;
    short8v a0 = *(const short8v*)(frow + kg * 8);
    short8v a1 = *(const short8v*)(frow + 32 + kg * 8);
    short8v a2 = *(const short8v*)(mrow + kg * 8);
    short8v a3 = *(const short8v*)(mrow + 32 + kg * 8);

    const short8v* wv8 = (const short8v*)wb;   // B-frags straight from L2

    #pragma unroll
    for (int q = 0; q < 2; ++q) {
        const int c4 = cp * 2 + q;
        float bv = bias[c4 * 16 + cl];
        f32x4 acc = (f32x4){bv, bv, bv, bv};
        acc = __builtin_amdgcn_mfma_f32_16x16x32_bf16(
            a0, wv8[(0 * 4 + c4) * 64 + lane], acc, 0, 0, 0);
        acc = __builtin_amdgcn_mfma_f32_16x16x32_bf16(
            a1, wv8[(1 * 4 + c4) * 64 + lane], acc, 0, 0, 0);
        acc = __builtin_amdgcn_mfma_f32_16x16x32_bf16(
            a2, wv8[(2 * 4 + c4) * 64 + lane], acc, 0, 0, 0);
        acc = __builtin_amdgcn_mfma_f32_16x16x32_bf16(
            a3, wv8[(3 * 4 + c4) * 64 + lane], acc, 0, 0, 0);
        #pragma unroll
        for (int r = 0; r < 4; ++r)
            out[(size_t)(n0 + rt * 16 + kg * 4 + r) * 64 + c4 * 16 + cl] = acc[r];
    }
}

extern "C" void kernel_launch(void* const* d_in, const int* in_sizes, int n_in,
                              void* d_out, int out_size, void* d_ws, size_t ws_size,
                              hipStream_t stream) {
    const float* feat = (const float*)d_in[0];
    const int*   eidx = (const int*)d_in[1];
    const float* W    = (const float*)d_in[2];
    const float* bias = (const float*)d_in[3];
    float* out = (float*)d_out;

    int* hist     = (int*)d_ws;                        // NBLK*NCB
    int* runstart = hist + NBLK * NCB;                 // NBLK*NCB
    int* boff     = runstart + NBLK * NCB;             // NCB + 2
    int* offs     = boff + NCB + 2;                    // N_NODES + 1
    int* csr      = offs + N_NODES + 1;                // N_EDGES
    ushort* wb    = (ushort*)(csr + N_EDGES);          // 8192 bf16 W frag table
    unsigned int* pairs = (unsigned int*)(wb + 8192);  // N_EDGES
    ushort* fb    = (ushort*)(pairs + N_EDGES);        // N_NODES*D bf16

    bin_hist<<<NBLK, 256, 0, stream>>>(eidx, hist, feat, fb, W, wb);
    rstart<<<NCB, 256, 0, stream>>>(hist, boff, runstart, offs);
    bin_fill<<<NBLK, 256, 0, stream>>>(eidx, runstart, pairs);
    fine_sort<<<NCB, 256, 0, stream>>>(pairs, boff, offs, csr);
    agg_gemm<<<N_NODES / 32, 256, 0, stream>>>(fb, offs, csr, wb, bias, out);
}

// Round 15
// 97.904 us; speedup vs baseline: 1.9471x; 1.9471x over previous
//
#include <hip/hip_runtime.h>

#define N_NODES 100000
#define D 64
#define N_EDGES 1200000
#define NCB 391              // coarse buckets of 256 dst nodes
#define NBLK 256             // partition blocks
#define PAD 16               // pad per-bucket total counters to 64B lines
#define CHUNK ((N_EDGES + NBLK - 1) / NBLK)   // 4688 edges per block

typedef __attribute__((ext_vector_type(8))) short short8v;           // 8 bf16 (MFMA frag)
typedef __attribute__((ext_vector_type(8))) unsigned short ushort8v; // 8 bf16 raw
typedef __attribute__((ext_vector_type(4))) float f32x4;

__device__ __forceinline__ unsigned short f2bf(float x) {
    unsigned int b = __float_as_uint(x);
    b += 0x7FFFu + ((b >> 16) & 1u);          // round-to-nearest-even
    return (unsigned short)(b >> 16);
}
__device__ __forceinline__ float bf2f(unsigned short u) {
    return __uint_as_float((unsigned int)u << 16);
}

// ---------- pass 1: per-block coarse histogram + bucket totals + fb + wb ----------
__global__ __launch_bounds__(256) void bin_hist(
    const int* __restrict__ eidx, int* __restrict__ hist, int* __restrict__ totP,
    const float* __restrict__ feat, ushort* __restrict__ fb,
    const float* __restrict__ W, ushort* __restrict__ wb)
{
    __shared__ int h[NCB];
    for (int i = threadIdx.x; i < NCB; i += 256) h[i] = 0;
    __syncthreads();
    const int blk = blockIdx.x;

    // W fragment table: wb[t][c4][lane][j] = bf16(W[32t+(lane>>4)*8+j][16c4+(lane&15)])
    if (blk < 32) {
        int g  = blk * 256 + threadIdx.x;     // 0..8191
        int j  = g & 7;
        int l  = (g >> 3) & 63;
        int c4 = (g >> 9) & 3;
        int tt = g >> 11;
        int k   = 32 * tt + ((l >> 4) << 3) + j;
        int col = 16 * c4 + (l & 15);
        wb[g] = f2bf(W[k * 64 + col]);
    }

    const int beg = blk * CHUNK;
    const int end = min(beg + CHUNK, N_EDGES);
    for (int e = beg + threadIdx.x; e < end; e += 256)
        atomicAdd(&h[eidx[N_EDGES + e] >> 8], 1);

    // folded bf16 conversion of the feature table
    const int total4 = N_NODES * D / 4;
    for (int i = blk * 256 + threadIdx.x; i < total4; i += NBLK * 256) {
        float4 v = ((const float4*)feat)[i];
        ushort4 o;
        o.x = f2bf(v.x); o.y = f2bf(v.y); o.z = f2bf(v.z); o.w = f2bf(v.w);
        ((ushort4*)fb)[i] = o;
    }

    __syncthreads();
    for (int i = threadIdx.x; i < NCB; i += 256) {
        int v = h[i];
        hist[blk * NCB + i] = v;
        if (v) atomicAdd(&totP[i * PAD], v);
    }
}

// ---------- pass 2: bucket bases + per-(block,bucket) run starts (parallel) ----------
// block i: bo_i = sum_{j<i} totP[j]; column scan of hist[.][i] over 256 blocks.
__global__ __launch_bounds__(256) void rstart(
    const int* __restrict__ totP, const int* __restrict__ hist,
    int* __restrict__ boff, int* __restrict__ runstart, int* __restrict__ offs)
{
    __shared__ int red[256];
    __shared__ int pfx[256];
    __shared__ int bo_s;

    const int tid = threadIdx.x;
    const int i   = blockIdx.x;

    int p = 0;
    for (int j = tid; j < i; j += 256) p += totP[j * PAD];
    red[tid] = p;
    __syncthreads();
    for (int off = 128; off > 0; off >>= 1) {
        if (tid < off) red[tid] += red[tid + off];
        __syncthreads();
    }
    if (tid == 0) {
        bo_s = red[0];
        boff[i] = red[0];
        if (i == 0) { boff[NCB] = N_EDGES; offs[N_NODES] = N_EDGES; }
    }
    __syncthreads();

    int v = hist[tid * NCB + i];
    pfx[tid] = v;
    __syncthreads();
    for (int off = 1; off < 256; off <<= 1) {
        int x = (tid >= off) ? pfx[tid - off] : 0;
        __syncthreads();
        pfx[tid] += x;
        __syncthreads();
    }
    runstart[tid * NCB + i] = bo_s + pfx[tid] - v;
}

// ---------- pass 3: deterministic scatter into per-block sub-ranges ----------
__global__ __launch_bounds__(256) void bin_fill(
    const int* __restrict__ eidx, const int* __restrict__ runstart,
    unsigned int* __restrict__ pairs)
{
    __shared__ int lcur[NCB];
    const int blk = blockIdx.x;
    for (int i = threadIdx.x; i < NCB; i += 256) lcur[i] = runstart[blk * NCB + i];
    __syncthreads();
    const int beg = blk * CHUNK;
    const int end = min(beg + CHUNK, N_EDGES);
    for (int e = beg + threadIdx.x; e < end; e += 256) {
        int src = eidx[e];
        int dst = eidx[N_EDGES + e];
        int pos = atomicAdd(&lcur[dst >> 8], 1);
        pairs[pos] = ((unsigned int)src << 8) | (unsigned int)(dst & 255);
    }
}

// ---------- pass 4: fine sort within bucket -> offs[] + csr[] ----------
__global__ __launch_bounds__(256) void fine_sort(
    const unsigned int* __restrict__ pairs,
    const int* __restrict__ boff,
    int* __restrict__ offs,
    int* __restrict__ csr)
{
    __shared__ int cnt[256];
    __shared__ int pfx[256];
    __shared__ int lcur[256];

    const int tid = threadIdx.x;
    const int b   = blockIdx.x;
    const int beg = boff[b];
    const int end = boff[b + 1];

    cnt[tid] = 0;
    __syncthreads();
    for (int j = beg + tid; j < end; j += 256)
        atomicAdd(&cnt[pairs[j] & 255], 1);
    __syncthreads();

    int v = cnt[tid];
    pfx[tid] = v;
    __syncthreads();
    for (int off = 1; off < 256; off <<= 1) {
        int x = (tid >= off) ? pfx[tid - off] : 0;
        __syncthreads();
        pfx[tid] += x;
        __syncthreads();
    }
    int ex = pfx[tid] - v;
    lcur[tid] = ex;
    int gn = b * 256 + tid;
    if (gn < N_NODES) offs[gn] = beg + ex;
    __syncthreads();

    for (int j = beg + tid; j < end; j += 256) {
        unsigned int p = pairs[j];
        int pos = beg + atomicAdd(&lcur[p & 255], 1);
        csr[pos] = (int)(p >> 8);
    }
}

// ---------- fused aggregate + MFMA linear: block = 32 nodes ----------
// Phase A: octet (8 lanes) per node, ushort8 (16B) gathers -> 64 rows in
// flight per wave; mean (bf16) -> LDS (4.6KB only -> high occupancy).
// Phase B: 4 waves x 2 MFMA tiles; B-frags straight from global wb (L2-hot).
#define MROW 72   // means row stride in ushorts (144B, 16B-aligned)
#define S8(j) (((bf2f(v0[j])+bf2f(v1[j]))+(bf2f(v2[j])+bf2f(v3[j]))) \
             + ((bf2f(v4[j])+bf2f(v5[j]))+(bf2f(v6[j])+bf2f(v7[j]))))
#define S4(j) ((bf2f(v0[j])+bf2f(v1[j]))+(bf2f(v2[j])+bf2f(v3[j])))
__global__ __launch_bounds__(256) void agg_gemm(
    const ushort* __restrict__ fb,
    const int* __restrict__ offs,
    const int* __restrict__ csr,
    const ushort* __restrict__ wb,
    const float* __restrict__ bias,
    float* __restrict__ out)
{
    __shared__ __attribute__((aligned(16))) ushort means[32 * MROW];

    const int tid = threadIdx.x;
    const int n0  = blockIdx.x * 32;

    // ----- Phase A: gather -----
    const int l    = tid & 7;                 // lane within octet (dims 8l..8l+7)
    const int node = tid >> 3;                // 0..31
    const int n    = n0 + node;

    const int beg = offs[n];
    const int end = offs[n + 1];
    const ushort8v* f8 = (const ushort8v*)fb;   // row stride = 8 ushort8v

    float s0=0.f,s1=0.f,s2=0.f,s3=0.f,s4=0.f,s5=0.f,s6=0.f,s7=0.f;
    int e = beg;
    for (; e + 8 <= end; e += 8) {
        int i0=csr[e+0], i1=csr[e+1], i2=csr[e+2], i3=csr[e+3];
        int i4=csr[e+4], i5=csr[e+5], i6=csr[e+6], i7=csr[e+7];
        ushort8v v0 = f8[(size_t)i0 * 8 + l];
        ushort8v v1 = f8[(size_t)i1 * 8 + l];
        ushort8v v2 = f8[(size_t)i2 * 8 + l];
        ushort8v v3 = f8[(size_t)i3 * 8 + l];
        ushort8v v4 = f8[(size_t)i4 * 8 + l];
        ushort8v v5 = f8[(size_t)i5 * 8 + l];
        ushort8v v6 = f8[(size_t)i6 * 8 + l];
        ushort8v v7 = f8[(size_t)i7 * 8 + l];
        s0 += S8(0); s1 += S8(1); s2 += S8(2); s3 += S8(3);
        s4 += S8(4); s5 += S8(5); s6 += S8(6); s7 += S8(7);
    }
    for (; e + 4 <= end; e += 4) {
        int i0=csr[e+0], i1=csr[e+1], i2=csr[e+2], i3=csr[e+3];
        ushort8v v0 = f8[(size_t)i0 * 8 + l];
        ushort8v v1 = f8[(size_t)i1 * 8 + l];
        ushort8v v2 = f8[(size_t)i2 * 8 + l];
        ushort8v v3 = f8[(size_t)i3 * 8 + l];
        s0 += S4(0); s1 += S4(1); s2 += S4(2); s3 += S4(3);
        s4 += S4(4); s5 += S4(5); s6 += S4(6); s7 += S4(7);
    }
    for (; e < end; ++e) {
        ushort8v v0 = f8[(size_t)csr[e] * 8 + l];
        s0 += bf2f(v0[0]); s1 += bf2f(v0[1]); s2 += bf2f(v0[2]); s3 += bf2f(v0[3]);
        s4 += bf2f(v0[4]); s5 += bf2f(v0[5]); s6 += bf2f(v0[6]); s7 += bf2f(v0[7]);
    }

    float dg = (float)(end - beg);
    dg = dg > 1.0f ? dg : 1.0f;
    float inv = 1.0f / dg;
    {
        ushort8v m;
        m[0]=f2bf(s0*inv); m[1]=f2bf(s1*inv); m[2]=f2bf(s2*inv); m[3]=f2bf(s3*inv);
        m[4]=f2bf(s4*inv); m[5]=f2bf(s5*inv); m[6]=f2bf(s6*inv); m[7]=f2bf(s7*inv);
        *(ushort8v*)(means + node * MROW + l * 8) = m;
    }
    __syncthreads();

    // ----- Phase B: MFMA. wave wv: row-tile rt = wv>>1 (16 nodes), col pair wv&1 -----
    const int lane = tid & 63;
    const int wv   = tid >> 6;
    const int rt   = wv >> 1;
    const int cp   = wv & 1;
    const int kg   = lane >> 4;
    const int cl   = lane & 15;

    const ushort* frow = fb + (size_t)(n0 + rt * 16 + cl) * 64;
    const ushort* mrow = means + (rt * 16 + cl) * MROW;
    short8v a0 = *(const short8v*)(frow + kg * 8);
    short8v a1 = *(const short8v*)(frow + 32 + kg * 8);
    short8v a2 = *(const short8v*)(mrow + kg * 8);
    short8v a3 = *(const short8v*)(mrow + 32 + kg * 8);

    const short8v* wv8 = (const short8v*)wb;   // B-frags straight from L2

    #pragma unroll
    for (int q = 0; q < 2; ++q) {
        const int c4 = cp * 2 + q;
        float bv = bias[c4 * 16 + cl];
        f32x4 acc = (f32x4){bv, bv, bv, bv};
        acc = __builtin_amdgcn_mfma_f32_16x16x32_bf16(
            a0, wv8[(0 * 4 + c4) * 64 + lane], acc, 0, 0, 0);
        acc = __builtin_amdgcn_mfma_f32_16x16x32_bf16(
            a1, wv8[(1 * 4 + c4) * 64 + lane], acc, 0, 0, 0);
        acc = __builtin_amdgcn_mfma_f32_16x16x32_bf16(
            a2, wv8[(2 * 4 + c4) * 64 + lane], acc, 0, 0, 0);
        acc = __builtin_amdgcn_mfma_f32_16x16x32_bf16(
            a3, wv8[(3 * 4 + c4) * 64 + lane], acc, 0, 0, 0);
        #pragma unroll
        for (int r = 0; r < 4; ++r)
            out[(size_t)(n0 + rt * 16 + kg * 4 + r) * 64 + c4 * 16 + cl] = acc[r];
    }
}

extern "C" void kernel_launch(void* const* d_in, const int* in_sizes, int n_in,
                              void* d_out, int out_size, void* d_ws, size_t ws_size,
                              hipStream_t stream) {
    const float* feat = (const float*)d_in[0];
    const int*   eidx = (const int*)d_in[1];
    const float* W    = (const float*)d_in[2];
    const float* bias = (const float*)d_in[3];
    float* out = (float*)d_out;

    int* hist     = (int*)d_ws;                        // NBLK*NCB
    int* totP     = hist + NBLK * NCB;                 // NCB*PAD (memset)
    int* runstart = totP + NCB * PAD;                  // NBLK*NCB
    int* boff     = runstart + NBLK * NCB;             // NCB + 2
    int* offs     = boff + NCB + 2;                    // N_NODES + 1
    int* csr      = offs + N_NODES + 1;                // N_EDGES
    ushort* wb    = (ushort*)(csr + N_EDGES);          // 8192 bf16 W frag table
    unsigned int* pairs = (unsigned int*)(wb + 8192);  // N_EDGES
    ushort* fb    = (ushort*)(pairs + N_EDGES);        // N_NODES*D bf16

    hipMemsetAsync(totP, 0, (size_t)NCB * PAD * sizeof(int), stream);

    bin_hist<<<NBLK, 256, 0, stream>>>(eidx, hist, totP, feat, fb, W, wb);
    rstart<<<NCB, 256, 0, stream>>>(totP, hist, boff, runstart, offs);
    bin_fill<<<NBLK, 256, 0, stream>>>(eidx, runstart, pairs);
    fine_sort<<<NCB, 256, 0, stream>>>(pairs, boff, offs, csr);
    agg_gemm<<<N_NODES / 32, 256, 0, stream>>>(fb, offs, csr, wb, bias, out);
}

// Round 16
// 89.696 us; speedup vs baseline: 2.1253x; 1.0915x over previous
//
#include <hip/hip_runtime.h>
#include <hip/hip_fp8.h>

#define N_NODES 100000
#define D 64
#define N_EDGES 1200000
#define NCB 391              // coarse buckets of 256 dst nodes
#define NBLK 256             // partition blocks
#define PAD 16               // pad per-bucket total counters to 64B lines
#define CHUNK ((N_EDGES + NBLK - 1) / NBLK)   // 4688 edges per block

typedef __attribute__((ext_vector_type(8))) short short8v;   // 8 bf16 (MFMA frag)
typedef __attribute__((ext_vector_type(4))) float f32x4;

__device__ __forceinline__ unsigned short f2bf(float x) {
    unsigned int b = __float_as_uint(x);
    b += 0x7FFFu + ((b >> 16) & 1u);          // round-to-nearest-even
    return (unsigned short)(b >> 16);
}
__device__ __forceinline__ unsigned char ftofp8(float x) {
    __hip_fp8_e4m3 q(x);                      // OCP e4m3, RNE+saturate
    return (unsigned char)q.__x;
}
#if __has_builtin(__builtin_amdgcn_cvt_f32_fp8)
#define F8D(w, s) __builtin_amdgcn_cvt_f32_fp8((w), (s))
#else
__device__ __forceinline__ float f8dec(unsigned int w, unsigned int s) {
    __hip_fp8_e4m3 q; q.__x = (unsigned char)(w >> (8 * s));
    return (float)q;
}
#define F8D(w, s) f8dec((w), (s))
#endif

// ---------- pass 1: per-block coarse histogram + bucket totals + fp8 table + wb ----------
__global__ __launch_bounds__(256) void bin_hist(
    const int* __restrict__ eidx, int* __restrict__ hist, int* __restrict__ totP,
    const float* __restrict__ feat, unsigned char* __restrict__ f8b,
    const float* __restrict__ W, ushort* __restrict__ wb)
{
    __shared__ int h[NCB];
    for (int i = threadIdx.x; i < NCB; i += 256) h[i] = 0;
    __syncthreads();
    const int blk = blockIdx.x;

    // W fragment table: wb[t][c4][lane][j] = bf16(W[32t+(lane>>4)*8+j][16c4+(lane&15)])
    if (blk < 32) {
        int g  = blk * 256 + threadIdx.x;     // 0..8191
        int j  = g & 7;
        int l  = (g >> 3) & 63;
        int c4 = (g >> 9) & 3;
        int tt = g >> 11;
        int k   = 32 * tt + ((l >> 4) << 3) + j;
        int col = 16 * c4 + (l & 15);
        wb[g] = f2bf(W[k * 64 + col]);
    }

    const int beg = blk * CHUNK;
    const int end = min(beg + CHUNK, N_EDGES);
    for (int e = beg + threadIdx.x; e < end; e += 256)
        atomicAdd(&h[eidx[N_EDGES + e] >> 8], 1);

    // fp8 conversion of the feature table (gather table, 6.4MB)
    const int total4 = N_NODES * D / 4;
    for (int i = blk * 256 + threadIdx.x; i < total4; i += NBLK * 256) {
        float4 v = ((const float4*)feat)[i];
        uchar4 o;
        o.x = ftofp8(v.x); o.y = ftofp8(v.y); o.z = ftofp8(v.z); o.w = ftofp8(v.w);
        ((uchar4*)f8b)[i] = o;
    }

    __syncthreads();
    for (int i = threadIdx.x; i < NCB; i += 256) {
        int v = h[i];
        hist[blk * NCB + i] = v;
        if (v) atomicAdd(&totP[i * PAD], v);
    }
}

// ---------- pass 2: bucket bases + per-(block,bucket) run starts (parallel) ----------
__global__ __launch_bounds__(256) void rstart(
    const int* __restrict__ totP, const int* __restrict__ hist,
    int* __restrict__ boff, int* __restrict__ runstart, int* __restrict__ offs)
{
    __shared__ int red[256];
    __shared__ int pfx[256];
    __shared__ int bo_s;

    const int tid = threadIdx.x;
    const int i   = blockIdx.x;

    int p = 0;
    for (int j = tid; j < i; j += 256) p += totP[j * PAD];
    red[tid] = p;
    __syncthreads();
    for (int off = 128; off > 0; off >>= 1) {
        if (tid < off) red[tid] += red[tid + off];
        __syncthreads();
    }
    if (tid == 0) {
        bo_s = red[0];
        boff[i] = red[0];
        if (i == 0) { boff[NCB] = N_EDGES; offs[N_NODES] = N_EDGES; }
    }
    __syncthreads();

    int v = hist[tid * NCB + i];
    pfx[tid] = v;
    __syncthreads();
    for (int off = 1; off < 256; off <<= 1) {
        int x = (tid >= off) ? pfx[tid - off] : 0;
        __syncthreads();
        pfx[tid] += x;
        __syncthreads();
    }
    runstart[tid * NCB + i] = bo_s + pfx[tid] - v;
}

// ---------- pass 3: deterministic scatter into per-block sub-ranges ----------
__global__ __launch_bounds__(256) void bin_fill(
    const int* __restrict__ eidx, const int* __restrict__ runstart,
    unsigned int* __restrict__ pairs)
{
    __shared__ int lcur[NCB];
    const int blk = blockIdx.x;
    for (int i = threadIdx.x; i < NCB; i += 256) lcur[i] = runstart[blk * NCB + i];
    __syncthreads();
    const int beg = blk * CHUNK;
    const int end = min(beg + CHUNK, N_EDGES);
    for (int e = beg + threadIdx.x; e < end; e += 256) {
        int src = eidx[e];
        int dst = eidx[N_EDGES + e];
        int pos = atomicAdd(&lcur[dst >> 8], 1);
        pairs[pos] = ((unsigned int)src << 8) | (unsigned int)(dst & 255);
    }
}

// ---------- pass 4: fine sort within bucket -> offs[] + csr[] ----------
__global__ __launch_bounds__(256) void fine_sort(
    const unsigned int* __restrict__ pairs,
    const int* __restrict__ boff,
    int* __restrict__ offs,
    int* __restrict__ csr)
{
    __shared__ int cnt[256];
    __shared__ int pfx[256];
    __shared__ int lcur[256];

    const int tid = threadIdx.x;
    const int b   = blockIdx.x;
    const int beg = boff[b];
    const int end = boff[b + 1];

    cnt[tid] = 0;
    __syncthreads();
    for (int j = beg + tid; j < end; j += 256)
        atomicAdd(&cnt[pairs[j] & 255], 1);
    __syncthreads();

    int v = cnt[tid];
    pfx[tid] = v;
    __syncthreads();
    for (int off = 1; off < 256; off <<= 1) {
        int x = (tid >= off) ? pfx[tid - off] : 0;
        __syncthreads();
        pfx[tid] += x;
        __syncthreads();
    }
    int ex = pfx[tid] - v;
    lcur[tid] = ex;
    int gn = b * 256 + tid;
    if (gn < N_NODES) offs[gn] = beg + ex;
    __syncthreads();

    for (int j = beg + tid; j < end; j += 256) {
        unsigned int p = pairs[j];
        int pos = beg + atomicAdd(&lcur[p & 255], 1);
        csr[pos] = (int)(p >> 8);
    }
}

// ---------- fused aggregate + MFMA linear: block = 32 nodes ----------
// Phase A: octet (8 lanes) per node, uint2 (8B) fp8 gathers (64B rows,
// 6.4MB table -> high L2 hit rate); mean (bf16) -> LDS.
// Phase B: 4 waves x 2 MFMA tiles; self-feats from f32 feat; B-frags from L2 wb.
#define MROW 72   // means row stride in ushorts (144B, 16B-aligned)
#define D8X(sel) (((F8D(w0.x,sel)+F8D(w1.x,sel))+(F8D(w2.x,sel)+F8D(w3.x,sel))) \
               + ((F8D(w4.x,sel)+F8D(w5.x,sel))+(F8D(w6.x,sel)+F8D(w7.x,sel))))
#define D8Y(sel) (((F8D(w0.y,sel)+F8D(w1.y,sel))+(F8D(w2.y,sel)+F8D(w3.y,sel))) \
               + ((F8D(w4.y,sel)+F8D(w5.y,sel))+(F8D(w6.y,sel)+F8D(w7.y,sel))))
#define D4X(sel) ((F8D(w0.x,sel)+F8D(w1.x,sel))+(F8D(w2.x,sel)+F8D(w3.x,sel)))
#define D4Y(sel) ((F8D(w0.y,sel)+F8D(w1.y,sel))+(F8D(w2.y,sel)+F8D(w3.y,sel)))
__global__ __launch_bounds__(256) void agg_gemm(
    const unsigned char* __restrict__ f8b,
    const float* __restrict__ feat,
    const int* __restrict__ offs,
    const int* __restrict__ csr,
    const ushort* __restrict__ wb,
    const float* __restrict__ bias,
    float* __restrict__ out)
{
    __shared__ __attribute__((aligned(16))) ushort means[32 * MROW];

    const int tid = threadIdx.x;
    const int n0  = blockIdx.x * 32;

    // ----- Phase A: gather -----
    const int l    = tid & 7;                 // lane within octet (dims 8l..8l+7)
    const int node = tid >> 3;                // 0..31
    const int n    = n0 + node;

    const int beg = offs[n];
    const int end = offs[n + 1];
    const uint2* g8 = (const uint2*)f8b;      // row = 8 uint2

    float s0=0.f,s1=0.f,s2=0.f,s3=0.f,s4=0.f,s5=0.f,s6=0.f,s7=0.f;
    int e = beg;
    for (; e + 8 <= end; e += 8) {
        int i0=csr[e+0], i1=csr[e+1], i2=csr[e+2], i3=csr[e+3];
        int i4=csr[e+4], i5=csr[e+5], i6=csr[e+6], i7=csr[e+7];
        uint2 w0 = g8[(size_t)i0 * 8 + l];
        uint2 w1 = g8[(size_t)i1 * 8 + l];
        uint2 w2 = g8[(size_t)i2 * 8 + l];
        uint2 w3 = g8[(size_t)i3 * 8 + l];
        uint2 w4 = g8[(size_t)i4 * 8 + l];
        uint2 w5 = g8[(size_t)i5 * 8 + l];
        uint2 w6 = g8[(size_t)i6 * 8 + l];
        uint2 w7 = g8[(size_t)i7 * 8 + l];
        s0 += D8X(0); s1 += D8X(1); s2 += D8X(2); s3 += D8X(3);
        s4 += D8Y(0); s5 += D8Y(1); s6 += D8Y(2); s7 += D8Y(3);
    }
    for (; e + 4 <= end; e += 4) {
        int i0=csr[e+0], i1=csr[e+1], i2=csr[e+2], i3=csr[e+3];
        uint2 w0 = g8[(size_t)i0 * 8 + l];
        uint2 w1 = g8[(size_t)i1 * 8 + l];
        uint2 w2 = g8[(size_t)i2 * 8 + l];
        uint2 w3 = g8[(size_t)i3 * 8 + l];
        s0 += D4X(0); s1 += D4X(1); s2 += D4X(2); s3 += D4X(3);
        s4 += D4Y(0); s5 += D4Y(1); s6 += D4Y(2); s7 += D4Y(3);
    }
    for (; e < end; ++e) {
        uint2 w0 = g8[(size_t)csr[e] * 8 + l];
        s0 += F8D(w0.x,0); s1 += F8D(w0.x,1); s2 += F8D(w0.x,2); s3 += F8D(w0.x,3);
        s4 += F8D(w0.y,0); s5 += F8D(w0.y,1); s6 += F8D(w0.y,2); s7 += F8D(w0.y,3);
    }

    float dg = (float)(end - beg);
    dg = dg > 1.0f ? dg : 1.0f;
    float inv = 1.0f / dg;
    {
        ushort s[8] = { f2bf(s0*inv), f2bf(s1*inv), f2bf(s2*inv), f2bf(s3*inv),
                        f2bf(s4*inv), f2bf(s5*inv), f2bf(s6*inv), f2bf(s7*inv) };
        *(ushort4*)(means + node * MROW + l * 8)     = *(ushort4*)&s[0];
        *(ushort4*)(means + node * MROW + l * 8 + 4) = *(ushort4*)&s[4];
    }
    __syncthreads();

    // ----- Phase B: MFMA. wave wv: row-tile rt = wv>>1 (16 nodes), col pair wv&1 -----
    const int lane = tid & 63;
    const int wv   = tid >> 6;
    const int rt   = wv >> 1;
    const int cp   = wv & 1;
    const int kg   = lane >> 4;
    const int cl   = lane & 15;

    // self-features straight from f32 feat -> bf16 fragments
    const float* frow = feat + (size_t)(n0 + rt * 16 + cl) * 64;
    f32x4 p0 = *(const f32x4*)(frow + kg * 8);
    f32x4 p1 = *(const f32x4*)(frow + kg * 8 + 4);
    f32x4 p2 = *(const f32x4*)(frow + 32 + kg * 8);
    f32x4 p3 = *(const f32x4*)(frow + 32 + kg * 8 + 4);
    short8v a0, a1;
    #pragma unroll
    for (int k = 0; k < 4; ++k) {
        a0[k]     = (short)f2bf(p0[k]);
        a0[k + 4] = (short)f2bf(p1[k]);
        a1[k]     = (short)f2bf(p2[k]);
        a1[k + 4] = (short)f2bf(p3[k]);
    }
    const ushort* mrow = means + (rt * 16 + cl) * MROW;
    short8v a2 = *(const short8v*)(mrow + kg * 8);
    short8v a3 = *(const short8v*)(mrow + 32 + kg * 8);

    const short8v* wv8 = (const short8v*)wb;   // B-frags straight from L2

    #pragma unroll
    for (int q = 0; q < 2; ++q) {
        const int c4 = cp * 2 + q;
        float bv = bias[c4 * 16 + cl];
        f32x4 acc = (f32x4){bv, bv, bv, bv};
        acc = __builtin_amdgcn_mfma_f32_16x16x32_bf16(
            a0, wv8[(0 * 4 + c4) * 64 + lane], acc, 0, 0, 0);
        acc = __builtin_amdgcn_mfma_f32_16x16x32_bf16(
            a1, wv8[(1 * 4 + c4) * 64 + lane], acc, 0, 0, 0);
        acc = __builtin_amdgcn_mfma_f32_16x16x32_bf16(
            a2, wv8[(2 * 4 + c4) * 64 + lane], acc, 0, 0, 0);
        acc = __builtin_amdgcn_mfma_f32_16x16x32_bf16(
            a3, wv8[(3 * 4 + c4) * 64 + lane], acc, 0, 0, 0);
        #pragma unroll
        for (int r = 0; r < 4; ++r)
            out[(size_t)(n0 + rt * 16 + kg * 4 + r) * 64 + c4 * 16 + cl] = acc[r];
    }
}

extern "C" void kernel_launch(void* const* d_in, const int* in_sizes, int n_in,
                              void* d_out, int out_size, void* d_ws, size_t ws_size,
                              hipStream_t stream) {
    const float* feat = (const float*)d_in[0];
    const int*   eidx = (const int*)d_in[1];
    const float* W    = (const float*)d_in[2];
    const float* bias = (const float*)d_in[3];
    float* out = (float*)d_out;

    // ws layout (all counts padded to 16B multiples)
    int* hist     = (int*)d_ws;                        // NBLK*NCB      (100096)
    int* totP     = hist + NBLK * NCB;                 // NCB*PAD       (6256, memset)
    int* runstart = totP + NCB * PAD;                  // NBLK*NCB      (100096)
    int* boff     = runstart + NBLK * NCB;             // NCB+5 -> 396
    int* offs     = boff + 396;                        // N_NODES+4     (100004)
    int* csr      = offs + 100004;                     // N_EDGES
    ushort* wb    = (ushort*)(csr + N_EDGES);          // 8192 bf16
    unsigned int* pairs = (unsigned int*)(wb + 8192);  // N_EDGES
    unsigned char* f8b  = (unsigned char*)(pairs + N_EDGES);  // N_NODES*64 fp8

    hipMemsetAsync(totP, 0, (size_t)NCB * PAD * sizeof(int), stream);

    bin_hist<<<NBLK, 256, 0, stream>>>(eidx, hist, totP, feat, f8b, W, wb);
    rstart<<<NCB, 256, 0, stream>>>(totP, hist, boff, runstart, offs);
    bin_fill<<<NBLK, 256, 0, stream>>>(eidx, runstart, pairs);
    fine_sort<<<NCB, 256, 0, stream>>>(pairs, boff, offs, csr);
    agg_gemm<<<N_NODES / 32, 256, 0, stream>>>(f8b, feat, offs, csr, wb, bias, out);
}